// Round 1
// baseline (262.603 us; speedup 1.0000x reference)
//
#include <hip/hip_runtime.h>
#include <math.h>

#define H 4096
#define INP 512
#define OUTN 64
#define H4 (H / 4)            // 1024 float4 per row
#define SPLITS 256
#define ROWS_PER_SPLIT (H / SPLITS)   // 16

// K1: partial[s*H + j] = sum_{i in split s} hidden[i] * (w[i,j] + plas[i,j]*hebb[i,j])
// grid (H/1024, SPLITS), block 256; each thread owns 4 consecutive j (float4)
__global__ __launch_bounds__(256) void k_partial(
    const float* __restrict__ hidden,
    const float* __restrict__ w,
    const float* __restrict__ plas,
    const float* __restrict__ hebb,
    float* __restrict__ partial)
{
    const int col4 = blockIdx.x * 256 + threadIdx.x;   // float4 column index 0..1023
    const int i0   = blockIdx.y * ROWS_PER_SPLIT;
    const float4* __restrict__ w4 = (const float4*)w;
    const float4* __restrict__ p4 = (const float4*)plas;
    const float4* __restrict__ h4 = (const float4*)hebb;

    float4 acc = make_float4(0.f, 0.f, 0.f, 0.f);
#pragma unroll 4
    for (int r = 0; r < ROWS_PER_SPLIT; ++r) {
        const int i = i0 + r;
        const float hv = hidden[i];                    // wave-uniform, scalar-cached
        const size_t idx = (size_t)i * H4 + col4;
        const float4 wv = w4[idx];
        const float4 pv = p4[idx];
        const float4 hb = h4[idx];
        acc.x += hv * (wv.x + pv.x * hb.x);
        acc.y += hv * (wv.y + pv.y * hb.y);
        acc.z += hv * (wv.z + pv.z * hb.z);
        acc.w += hv * (wv.w + pv.w * hb.w);
    }
    ((float4*)partial)[(size_t)blockIdx.y * H4 + col4] = acc;
}

// K2: per j — reduce SPLITS partials + inp @ W_i2h[j,:] + b, relu -> x[j]
// one wave (64 lanes) per j; block 256 = 4 waves; grid H/4
__global__ __launch_bounds__(256) void k_finish_x(
    const float* __restrict__ partial,
    const float* __restrict__ inp,
    const float* __restrict__ W_i2h,
    const float* __restrict__ b_i2h,
    float* __restrict__ x_out)
{
    const int wave = threadIdx.x >> 6;
    const int lane = threadIdx.x & 63;
    const int j = blockIdx.x * 4 + wave;

    float sum = 0.f;
#pragma unroll
    for (int s = lane; s < SPLITS; s += 64)
        sum += partial[(size_t)s * H + j];

    const float4* __restrict__ row4 = (const float4*)(W_i2h + (size_t)j * INP);
    const float4* __restrict__ in4  = (const float4*)inp;
#pragma unroll
    for (int c = lane; c < INP / 4; c += 64) {
        const float4 a = row4[c];
        const float4 b = in4[c];
        sum += a.x * b.x + a.y * b.y + a.z * b.z + a.w * b.w;
    }
#pragma unroll
    for (int off = 32; off > 0; off >>= 1)
        sum += __shfl_down(sum, off, 64);

    if (lane == 0) {
        const float pre = sum + b_i2h[j];
        x_out[j] = pre > 0.f ? pre : 0.f;
    }
}

// K3: hebb_new[i,j] = (1-learn)*hebb[i,j] + learn*hidden[i]*x[j]
// one block per row i, float4 streaming
__global__ __launch_bounds__(256) void k_hebb(
    const float* __restrict__ hebb,
    const float* __restrict__ hidden,
    const float* __restrict__ x,
    const float* __restrict__ learn,
    float* __restrict__ hebb_out)
{
    const int i = blockIdx.x;
    const float lr = learn[0];
    const float om = 1.f - lr;
    const float coef = lr * hidden[i];
    const float4* __restrict__ hb4 = (const float4*)hebb;
    const float4* __restrict__ x4  = (const float4*)x;
    float4* __restrict__ o4 = (float4*)hebb_out;
    const size_t base = (size_t)i * H4;
#pragma unroll
    for (int c = threadIdx.x; c < H4; c += 256) {
        const float4 h  = hb4[base + c];
        const float4 xv = x4[c];
        float4 r;
        r.x = om * h.x + coef * xv.x;
        r.y = om * h.y + coef * xv.y;
        r.z = om * h.z + coef * xv.z;
        r.w = om * h.w + coef * xv.w;
        o4[base + c] = r;
    }
}

// K4: out[o] = tanh(x @ W_h2o[o,:] + b_h2o[o]); one block per o
__global__ __launch_bounds__(256) void k_out(
    const float* __restrict__ x,
    const float* __restrict__ W_h2o,
    const float* __restrict__ b_h2o,
    float* __restrict__ out)
{
    const int o = blockIdx.x;
    const float4* __restrict__ row4 = (const float4*)(W_h2o + (size_t)o * H);
    const float4* __restrict__ x4   = (const float4*)x;
    float sum = 0.f;
#pragma unroll
    for (int c = threadIdx.x; c < H4; c += 256) {
        const float4 a = row4[c];
        const float4 b = x4[c];
        sum += a.x * b.x + a.y * b.y + a.z * b.z + a.w * b.w;
    }
#pragma unroll
    for (int off = 32; off > 0; off >>= 1)
        sum += __shfl_down(sum, off, 64);
    __shared__ float red[4];
    const int lane = threadIdx.x & 63;
    const int wave = threadIdx.x >> 6;
    if (lane == 0) red[wave] = sum;
    __syncthreads();
    if (threadIdx.x == 0) {
        const float s = red[0] + red[1] + red[2] + red[3];
        out[o] = tanhf(s + b_h2o[o]);
    }
}

extern "C" void kernel_launch(void* const* d_in, const int* in_sizes, int n_in,
                              void* d_out, int out_size, void* d_ws, size_t ws_size,
                              hipStream_t stream)
{
    const float* inp    = (const float*)d_in[0];
    const float* hidden = (const float*)d_in[1];
    const float* hebb   = (const float*)d_in[2];
    const float* W_i2h  = (const float*)d_in[3];
    const float* b_i2h  = (const float*)d_in[4];
    const float* w      = (const float*)d_in[5];
    const float* plas   = (const float*)d_in[6];
    const float* learn  = (const float*)d_in[7];
    const float* W_h2o  = (const float*)d_in[8];
    const float* b_h2o  = (const float*)d_in[9];

    float* out      = (float*)d_out;        // [64]
    float* x        = out + OUTN;           // [4096]
    float* hebb_out = x + H;                // [4096*4096]

    // Scratch for split-K partials: 256*4096 floats = 4 MB.
    // Prefer d_ws; if too small, borrow the (not-yet-written) hebb output region —
    // stream order guarantees k_finish_x consumes it before k_hebb overwrites.
    const size_t part_bytes = (size_t)SPLITS * H * sizeof(float);
    float* partial = (ws_size >= part_bytes) ? (float*)d_ws : hebb_out;

    k_partial<<<dim3(H / 1024, SPLITS), 256, 0, stream>>>(hidden, w, plas, hebb, partial);
    k_finish_x<<<H / 4, 256, 0, stream>>>(partial, inp, W_i2h, b_i2h, x);
    k_hebb<<<H, 256, 0, stream>>>(hebb, hidden, x, learn, hebb_out);
    k_out<<<OUTN, 256, 0, stream>>>(x, W_h2o, b_h2o, out);
}